// Round 7
// baseline (113.974 us; speedup 1.0000x reference)
//
#include <hip/hip_runtime.h>

#define BATCH 16384
#define LATENT 128
#define HIDDEN 64
#define INDIM 100
#define KPAD 128
#define TANH_SCALE 2.885390081777927f   // 2*log2(e): exp(2x) = exp2(SCALE*x)

typedef short shortx8 __attribute__((ext_vector_type(8)));
typedef float floatx4 __attribute__((ext_vector_type(4)));

__device__ __forceinline__ unsigned bfbits(float f) {
    union { float f; unsigned u; } v; v.f = f;
    return (v.u + 0x7FFF + ((v.u >> 16) & 1)) >> 16;   // RNE, inputs finite
}

#if __has_builtin(__builtin_amdgcn_exp2f)
#define EXP2F(x) __builtin_amdgcn_exp2f(x)
#else
#define EXP2F(x) __exp2f(x)
#endif
#if __has_builtin(__builtin_amdgcn_rcpf)
#define RCPF(x) __builtin_amdgcn_rcpf(x)
#else
#define RCPF(x) (1.0f / (x))
#endif

#define N_U_BLK (BATCH / 16)                 // 1024 16-row tiles of u
#define N_W_BLK (LATENT * HIDDEN / 16)       // 512  16-row tiles of W1

// ---------------------------------------------------------------------------
// prep v3: 16-row LDS-transpose tiles, one tile per 256-thr block, 1537 blocks
// (R6's prep was the hidden 50+us: stride-400B scatter reads + divergent
// tails; R4's LDS prep was right in kind but 384 blocks = 1.5 waves/CU).
// Phase 1: coalesced float2 row reads -> bf16 pairs -> LDS [16][136].
//          k=100 gets 1.0 (u) or b1*TANH_SCALE (W1); k in (100,128) zero.
// Phase 2: one ds_read_b128 (fragment gather) + one coalesced 16B global
//          write per thread. Output layout byte-identical to R5/R6's proven
//          uf/wf. W1/b1 pre-scaled by 2*log2(e) (exp2 feeds directly).
// Block N_U_BLK+N_W_BLK computes b2eff = b2 + rowsum(W2).
// ---------------------------------------------------------------------------
__global__ __launch_bounds__(256) void prep_all(const float* __restrict__ u,
                                                const float* __restrict__ W1,
                                                const float* __restrict__ b1,
                                                const float* __restrict__ W2,
                                                const float* __restrict__ b2,
                                                shortx8* __restrict__ uf,
                                                shortx8* __restrict__ wf,
                                                float* __restrict__ b2eff) {
    int bx = blockIdx.x;
    int tid = threadIdx.x;

    if (bx >= N_U_BLK + N_W_BLK) {           // b2eff block
        if (tid < LATENT) {
            float s = b2[tid];
            const float* wp = W2 + tid * HIDDEN;
#pragma unroll 8
            for (int h = 0; h < HIDDEN; h++) s += wp[h];
            b2eff[tid] = s;
        }
        return;
    }

    bool isW = (bx >= N_U_BLK);
    int tileIdx = isW ? (bx - N_U_BLK) : bx;     // 16-row tile index
    int r0 = tileIdx * 16;                       // first source row
    const float* src = isW ? W1 : u;
    float scale = isW ? TANH_SCALE : 1.0f;

    __shared__ short lds[16 * 136];

    // Phase 1: 1024 bf16-pairs (16 rows x 64 k-pairs), 4 per thread, coalesced
#pragma unroll
    for (int it = 0; it < 4; it++) {
        int p = it * 256 + tid;
        int rl = p >> 6;                         // 0..15
        int kp = (p & 63) * 2;                   // even k
        float f0 = 0.0f, f1 = 0.0f;
        if (kp < INDIM) {                        // kp<=98 -> kp+1<=99 valid
            const float2 t = *(const float2*)(src + (r0 + rl) * INDIM + kp);
            f0 = t.x * scale; f1 = t.y * scale;
        } else if (kp == INDIM) {
            f0 = isW ? b1[r0 + rl] * TANH_SCALE : 1.0f;
        }
        *(unsigned*)(&lds[rl * 136 + kp]) = bfbits(f0) | (bfbits(f1) << 16);
    }
    __syncthreads();

    // Phase 2: 256 threads = 4 kt-chunks x 64 lanes, one 16B write each
    {
        int lane = tid & 63;
        int kt = tid >> 6;
        int rl = lane & 15;
        int kb = kt * 32 + ((lane >> 4) << 3);
        shortx8 v = *(const shortx8*)(&lds[rl * 136 + kb]);
        shortx8* dst = isW ? wf : uf;
        dst[((size_t)tileIdx * 4 + kt) * 64 + lane] = v;
    }
}

// ---------------------------------------------------------------------------
// Weight-stationary main kernel (R6 structure, proven). Wave = ONE latent:
// afr[4][4] loads once; 8 batch-groups of 16 rows stream through.
// Change vs R6: cross-quad reduction + store DEFERRED to wave end (sg[8]),
// so the per-g body is pure MFMA+VALU and g+1's MFMAs overlap g's epilogue
// without waiting on the serial shuffle/store chain.
// Epilogue algebra: tanh scale folded into W1 (exp2 direct); sum_h W2 folded
// into b2eff; per tanh: exp2, add, rcp, fma(-2*w2*rr).
// ---------------------------------------------------------------------------
__global__ __launch_bounds__(256, 4) void branch_mlp(const shortx8* __restrict__ uf,
                                                     const shortx8* __restrict__ wf,
                                                     const float* __restrict__ W2,
                                                     const float* __restrict__ b2eff,
                                                     float* __restrict__ out) {
    int tid = threadIdx.x;
    int lane = tid & 63;
    int w = tid >> 6;
    int bx = blockIdx.x;
    int lat = bx >> 5;
    int G0 = (bx & 31) * 32 + w * 8;          // first of 8 batch 16-row groups
    int q = lane >> 4;

    // latent-resident weights: 16 fragment chunks (64 VGPRs)
    shortx8 afr[4][4];
    const shortx8* wb = wf + (size_t)lat * 16 * 64 + lane;
#pragma unroll
    for (int nt = 0; nt < 4; nt++)
#pragma unroll
        for (int kt = 0; kt < 4; kt++)
            afr[nt][kt] = wb[(nt * 4 + kt) * 64];

    // -2*W2 for this lane's 16 h-values (h = nt*16 + q*4 + r)
    float4 w2v[4];
#pragma unroll
    for (int nt = 0; nt < 4; nt++) {
        float4 t = *(const float4*)(W2 + lat * HIDDEN + nt * 16 + q * 4);
        w2v[nt] = make_float4(-2.0f * t.x, -2.0f * t.y, -2.0f * t.z, -2.0f * t.w);
    }
    float b2v = b2eff[lat];

    const shortx8* ua = uf + (size_t)G0 * 4 * 64 + lane;

    float sg[8];
#pragma unroll
    for (int g = 0; g < 8; g++) {
        shortx8 ub[4];
#pragma unroll
        for (int kt = 0; kt < 4; kt++)
            ub[kt] = ua[(g * 4 + kt) * 64];

        floatx4 acc[4] = {};   // [nt]: rows h, cols batch
#pragma unroll
        for (int kt = 0; kt < 4; kt++)
#pragma unroll
            for (int nt = 0; nt < 4; nt++)
                acc[nt] = __builtin_amdgcn_mfma_f32_16x16x32_bf16(afr[nt][kt], ub[kt], acc[nt], 0, 0, 0);

        float s = 0.0f;
#pragma unroll
        for (int nt = 0; nt < 4; nt++)
#pragma unroll
            for (int r = 0; r < 4; r++) {
                float e = EXP2F(acc[nt][r]);          // = exp(2x)
                float rr = RCPF(e + 1.0f);
                s = fmaf((&w2v[nt].x)[r], rr, s);     // s += -2*w2*rr
            }
        sg[g] = s;
    }

    // deferred reductions: 16 independent shuffles pipeline together
#pragma unroll
    for (int g = 0; g < 8; g++) sg[g] += __shfl_xor(sg[g], 16, 64);
#pragma unroll
    for (int g = 0; g < 8; g++) sg[g] += __shfl_xor(sg[g], 32, 64);
    if (lane < 16) {
        float* outp = out + ((size_t)G0 * 16 + lane) * LATENT + lat;
#pragma unroll
        for (int g = 0; g < 8; g++)
            outp[g * 16 * LATENT] = sg[g] + b2v;
    }
}

// --- fp32 fallback (no workspace needed) ---
__global__ __launch_bounds__(256) void fallback_kernel(const float* __restrict__ u, const float* __restrict__ W1,
                                                       const float* __restrict__ b1, const float* __restrict__ W2,
                                                       const float* __restrict__ b2, float* __restrict__ out) {
    int idx = blockIdx.x * 256 + threadIdx.x;
    if (idx >= BATCH * LATENT) return;
    int b = idx >> 7;
    int lat = idx & 127;
    const float* ub = u + b * INDIM;
    float s = 0.0f;
    for (int h = 0; h < HIDDEN; h++) {
        const float* wp = W1 + (lat * HIDDEN + h) * INDIM;
        float dd = b1[lat * HIDDEN + h];
        for (int k = 0; k < INDIM; k++) dd += ub[k] * wp[k];
        s += tanhf(dd) * W2[lat * HIDDEN + h];
    }
    out[idx] = s + b2[lat];
}

extern "C" void kernel_launch(void* const* d_in, const int* in_sizes, int n_in,
                              void* d_out, int out_size, void* d_ws, size_t ws_size,
                              hipStream_t stream) {
    const float* u  = (const float*)d_in[0];
    const float* W1 = (const float*)d_in[1];
    const float* b1 = (const float*)d_in[2];
    const float* W2 = (const float*)d_in[3];
    const float* b2 = (const float*)d_in[4];
    float* out = (float*)d_out;

    const size_t UF_BYTES = (size_t)BATCH * KPAD * 2;           // 4 MiB
    const size_t WF_BYTES = (size_t)LATENT * HIDDEN * KPAD * 2; // 2 MiB
    const size_t B2_BYTES = LATENT * sizeof(float);

    if (ws_size < UF_BYTES + WF_BYTES + B2_BYTES) {
        fallback_kernel<<<(BATCH * LATENT + 255) / 256, 256, 0, stream>>>(u, W1, b1, W2, b2, out);
        return;
    }

    shortx8* uf = (shortx8*)d_ws;
    shortx8* wf = (shortx8*)((char*)d_ws + UF_BYTES);
    float* b2eff = (float*)((char*)d_ws + UF_BYTES + WF_BYTES);

    prep_all<<<N_U_BLK + N_W_BLK + 1, 256, 0, stream>>>(u, W1, b1, W2, b2, uf, wf, b2eff);
    branch_mlp<<<4096, 256, 0, stream>>>(uf, wf, W2, b2eff, out);
}

// Round 8
// 113.917 us; speedup vs baseline: 1.0005x; 1.0005x over previous
//
#include <hip/hip_runtime.h>

#define BATCH 16384
#define LATENT 128
#define HIDDEN 64
#define INDIM 100
#define KPAD 128
#define TANH_SCALE 2.885390081777927f   // 2*log2(e): exp(2x) = exp2(SCALE*x)

typedef short shortx8 __attribute__((ext_vector_type(8)));
typedef float floatx4 __attribute__((ext_vector_type(4)));

__device__ __forceinline__ unsigned bfbits(float f) {
    union { float f; unsigned u; } v; v.f = f;
    return (v.u + 0x7FFF + ((v.u >> 16) & 1)) >> 16;   // RNE, inputs finite
}

#if __has_builtin(__builtin_amdgcn_exp2f)
#define EXP2F(x) __builtin_amdgcn_exp2f(x)
#else
#define EXP2F(x) __exp2f(x)
#endif
#if __has_builtin(__builtin_amdgcn_rcpf)
#define RCPF(x) __builtin_amdgcn_rcpf(x)
#else
#define RCPF(x) (1.0f / (x))
#endif

#define N_U_BLK (BATCH / 16)                 // 1024 16-row tiles of u
#define N_W_BLK (LATENT * HIDDEN / 16)       // 512  16-row tiles of W1

// ---------------------------------------------------------------------------
// prep (R7, proven): 16-row LDS-transpose tiles, one per 256-thr block.
// Phase 1: coalesced float2 row reads -> bf16 pairs -> LDS [16][136].
// Phase 2: ds_read_b128 fragment gather + coalesced 16B global write.
// W1/b1 pre-scaled by 2*log2(e); k=100 carries bias (1.0 for u, b1 for W1).
// Last block: b2eff = b2 + rowsum(W2).
// ---------------------------------------------------------------------------
__global__ __launch_bounds__(256) void prep_all(const float* __restrict__ u,
                                                const float* __restrict__ W1,
                                                const float* __restrict__ b1,
                                                const float* __restrict__ W2,
                                                const float* __restrict__ b2,
                                                shortx8* __restrict__ uf,
                                                shortx8* __restrict__ wf,
                                                float* __restrict__ b2eff) {
    int bx = blockIdx.x;
    int tid = threadIdx.x;

    if (bx >= N_U_BLK + N_W_BLK) {           // b2eff block
        if (tid < LATENT) {
            float s = b2[tid];
            const float* wp = W2 + tid * HIDDEN;
#pragma unroll 8
            for (int h = 0; h < HIDDEN; h++) s += wp[h];
            b2eff[tid] = s;
        }
        return;
    }

    bool isW = (bx >= N_U_BLK);
    int tileIdx = isW ? (bx - N_U_BLK) : bx;
    int r0 = tileIdx * 16;
    const float* src = isW ? W1 : u;
    float scale = isW ? TANH_SCALE : 1.0f;

    __shared__ short lds[16 * 136];

#pragma unroll
    for (int it = 0; it < 4; it++) {
        int p = it * 256 + tid;
        int rl = p >> 6;
        int kp = (p & 63) * 2;
        float f0 = 0.0f, f1 = 0.0f;
        if (kp < INDIM) {
            const float2 t = *(const float2*)(src + (r0 + rl) * INDIM + kp);
            f0 = t.x * scale; f1 = t.y * scale;
        } else if (kp == INDIM) {
            f0 = isW ? b1[r0 + rl] * TANH_SCALE : 1.0f;
        }
        *(unsigned*)(&lds[rl * 136 + kp]) = bfbits(f0) | (bfbits(f1) << 16);
    }
    __syncthreads();

    {
        int lane = tid & 63;
        int kt = tid >> 6;
        int rl = lane & 15;
        int kb = kt * 32 + ((lane >> 4) << 3);
        shortx8 v = *(const shortx8*)(&lds[rl * 136 + kb]);
        shortx8* dst = isW ? wf : uf;
        dst[((size_t)tileIdx * 4 + kt) * 64 + lane] = v;
    }
}

// ---------------------------------------------------------------------------
// Weight-stationary main kernel. Wave = ONE latent; 8 batch-groups stream.
// R8 changes vs R7:
//  (1) ub DOUBLE-BUFFER: g+1's 4 fragment chunks load before g's epilogue,
//      so the ~450-cyc epilogue hides the L2 latency that R7 exposed
//      (VGPR=64 showed just-in-time loads; ~12us of stalls).
//  (2) PAIRED RCP: one v_rcp serves two tanh via 1/(d0*d1) algebra
//      (trans ops per 16-value epilogue: 32 -> 24; trans pipe is the wall).
// Epilogue algebra (proven R6): scale folded into W1 -> exp2 direct;
// sum_h W2 folded into b2eff; s += -2*w2/(exp2(y)+1).
// ---------------------------------------------------------------------------
__global__ __launch_bounds__(256, 2) void branch_mlp(const shortx8* __restrict__ uf,
                                                     const shortx8* __restrict__ wf,
                                                     const float* __restrict__ W2,
                                                     const float* __restrict__ b2eff,
                                                     float* __restrict__ out) {
    int tid = threadIdx.x;
    int lane = tid & 63;
    int w = tid >> 6;
    int bx = blockIdx.x;
    int lat = bx >> 5;
    int G0 = (bx & 31) * 32 + w * 8;
    int q = lane >> 4;

    // latent-resident weights: 16 fragment chunks
    shortx8 afr[4][4];
    const shortx8* wb = wf + (size_t)lat * 16 * 64 + lane;
#pragma unroll
    for (int nt = 0; nt < 4; nt++)
#pragma unroll
        for (int kt = 0; kt < 4; kt++)
            afr[nt][kt] = wb[(nt * 4 + kt) * 64];

    // -2*W2 for this lane's 16 h-values (h = nt*16 + q*4 + r)
    float4 w2v[4];
#pragma unroll
    for (int nt = 0; nt < 4; nt++) {
        float4 t = *(const float4*)(W2 + lat * HIDDEN + nt * 16 + q * 4);
        w2v[nt] = make_float4(-2.0f * t.x, -2.0f * t.y, -2.0f * t.z, -2.0f * t.w);
    }
    float b2v = b2eff[lat];

    const shortx8* ua = uf + (size_t)G0 * 4 * 64 + lane;

    shortx8 ub[2][4];
#pragma unroll
    for (int kt = 0; kt < 4; kt++) ub[0][kt] = ua[kt * 64];

    float sg[8];
#pragma unroll
    for (int g = 0; g < 8; g++) {
        int cur = g & 1, nxt = cur ^ 1;
        if (g < 7) {
#pragma unroll
            for (int kt = 0; kt < 4; kt++)
                ub[nxt][kt] = ua[((g + 1) * 4 + kt) * 64];
        }

        floatx4 acc[4] = {};   // [nt]: rows h, cols batch
#pragma unroll
        for (int kt = 0; kt < 4; kt++)
#pragma unroll
            for (int nt = 0; nt < 4; nt++)
                acc[nt] = __builtin_amdgcn_mfma_f32_16x16x32_bf16(afr[nt][kt], ub[cur][kt], acc[nt], 0, 0, 0);

        float s = 0.0f;
#pragma unroll
        for (int nt = 0; nt < 4; nt++)
#pragma unroll
            for (int r = 0; r < 4; r += 2) {
                float e0 = EXP2F(acc[nt][r]);         // = exp(2x)
                float e1 = EXP2F(acc[nt][r + 1]);
                float d0 = e0 + 1.0f, d1 = e1 + 1.0f;
                float ip = RCPF(d0 * d1);             // one rcp per two tanh
                s = fmaf((&w2v[nt].x)[r],     ip * d1, s);
                s = fmaf((&w2v[nt].x)[r + 1], ip * d0, s);
            }
        sg[g] = s;
    }

    // deferred cross-quad reductions + stores
#pragma unroll
    for (int g = 0; g < 8; g++) sg[g] += __shfl_xor(sg[g], 16, 64);
#pragma unroll
    for (int g = 0; g < 8; g++) sg[g] += __shfl_xor(sg[g], 32, 64);
    if (lane < 16) {
        float* outp = out + ((size_t)G0 * 16 + lane) * LATENT + lat;
#pragma unroll
        for (int g = 0; g < 8; g++)
            outp[g * 16 * LATENT] = sg[g] + b2v;
    }
}

// --- fp32 fallback (no workspace needed) ---
__global__ __launch_bounds__(256) void fallback_kernel(const float* __restrict__ u, const float* __restrict__ W1,
                                                       const float* __restrict__ b1, const float* __restrict__ W2,
                                                       const float* __restrict__ b2, float* __restrict__ out) {
    int idx = blockIdx.x * 256 + threadIdx.x;
    if (idx >= BATCH * LATENT) return;
    int b = idx >> 7;
    int lat = idx & 127;
    const float* ub = u + b * INDIM;
    float s = 0.0f;
    for (int h = 0; h < HIDDEN; h++) {
        const float* wp = W1 + (lat * HIDDEN + h) * INDIM;
        float dd = b1[lat * HIDDEN + h];
        for (int k = 0; k < INDIM; k++) dd += ub[k] * wp[k];
        s += tanhf(dd) * W2[lat * HIDDEN + h];
    }
    out[idx] = s + b2[lat];
}

extern "C" void kernel_launch(void* const* d_in, const int* in_sizes, int n_in,
                              void* d_out, int out_size, void* d_ws, size_t ws_size,
                              hipStream_t stream) {
    const float* u  = (const float*)d_in[0];
    const float* W1 = (const float*)d_in[1];
    const float* b1 = (const float*)d_in[2];
    const float* W2 = (const float*)d_in[3];
    const float* b2 = (const float*)d_in[4];
    float* out = (float*)d_out;

    const size_t UF_BYTES = (size_t)BATCH * KPAD * 2;           // 4 MiB
    const size_t WF_BYTES = (size_t)LATENT * HIDDEN * KPAD * 2; // 2 MiB
    const size_t B2_BYTES = LATENT * sizeof(float);

    if (ws_size < UF_BYTES + WF_BYTES + B2_BYTES) {
        fallback_kernel<<<(BATCH * LATENT + 255) / 256, 256, 0, stream>>>(u, W1, b1, W2, b2, out);
        return;
    }

    shortx8* uf = (shortx8*)d_ws;
    shortx8* wf = (shortx8*)((char*)d_ws + UF_BYTES);
    float* b2eff = (float*)((char*)d_ws + UF_BYTES + WF_BYTES);

    prep_all<<<N_U_BLK + N_W_BLK + 1, 256, 0, stream>>>(u, W1, b1, W2, b2, uf, wf, b2eff);
    branch_mlp<<<4096, 256, 0, stream>>>(uf, wf, W2, b2eff, out);
}

// Round 9
// 113.163 us; speedup vs baseline: 1.0072x; 1.0067x over previous
//
#include <hip/hip_runtime.h>

#define BATCH 16384
#define LATENT 128
#define HIDDEN 64
#define INDIM 100
#define KPAD 128
#define TANH_SCALE 2.885390081777927f   // 2*log2(e): exp(2x) = exp2(SCALE*x)

typedef short shortx8 __attribute__((ext_vector_type(8)));
typedef float floatx4 __attribute__((ext_vector_type(4)));

__device__ __forceinline__ unsigned bfbits(float f) {
    union { float f; unsigned u; } v; v.f = f;
    return (v.u + 0x7FFF + ((v.u >> 16) & 1)) >> 16;   // RNE, inputs finite
}

#if __has_builtin(__builtin_amdgcn_exp2f)
#define EXP2F(x) __builtin_amdgcn_exp2f(x)
#else
#define EXP2F(x) __exp2f(x)
#endif
#if __has_builtin(__builtin_amdgcn_rcpf)
#define RCPF(x) __builtin_amdgcn_rcpf(x)
#else
#define RCPF(x) (1.0f / (x))
#endif

#define N_U_BLK (BATCH / 16)                 // 1024 16-row tiles of u
#define N_W_BLK (LATENT * HIDDEN / 16)       // 512  16-row tiles of W1

// ---------------------------------------------------------------------------
// prep (R7, proven): 16-row LDS-transpose tiles, one per 256-thr block.
// ---------------------------------------------------------------------------
__global__ __launch_bounds__(256) void prep_all(const float* __restrict__ u,
                                                const float* __restrict__ W1,
                                                const float* __restrict__ b1,
                                                const float* __restrict__ W2,
                                                const float* __restrict__ b2,
                                                shortx8* __restrict__ uf,
                                                shortx8* __restrict__ wf,
                                                float* __restrict__ b2eff) {
    int bx = blockIdx.x;
    int tid = threadIdx.x;

    if (bx >= N_U_BLK + N_W_BLK) {           // b2eff block
        if (tid < LATENT) {
            float s = b2[tid];
            const float* wp = W2 + tid * HIDDEN;
#pragma unroll 8
            for (int h = 0; h < HIDDEN; h++) s += wp[h];
            b2eff[tid] = s;
        }
        return;
    }

    bool isW = (bx >= N_U_BLK);
    int tileIdx = isW ? (bx - N_U_BLK) : bx;
    int r0 = tileIdx * 16;
    const float* src = isW ? W1 : u;
    float scale = isW ? TANH_SCALE : 1.0f;

    __shared__ short lds[16 * 136];

#pragma unroll
    for (int it = 0; it < 4; it++) {
        int p = it * 256 + tid;
        int rl = p >> 6;
        int kp = (p & 63) * 2;
        float f0 = 0.0f, f1 = 0.0f;
        if (kp < INDIM) {
            const float2 t = *(const float2*)(src + (r0 + rl) * INDIM + kp);
            f0 = t.x * scale; f1 = t.y * scale;
        } else if (kp == INDIM) {
            f0 = isW ? b1[r0 + rl] * TANH_SCALE : 1.0f;
        }
        *(unsigned*)(&lds[rl * 136 + kp]) = bfbits(f0) | (bfbits(f1) << 16);
    }
    __syncthreads();

    {
        int lane = tid & 63;
        int kt = tid >> 6;
        int rl = lane & 15;
        int kb = kt * 32 + ((lane >> 4) << 3);
        shortx8 v = *(const shortx8*)(&lds[rl * 136 + kb]);
        shortx8* dst = isW ? wf : uf;
        dst[((size_t)tileIdx * 4 + kt) * 64 + lane] = v;
    }
}

// ---------------------------------------------------------------------------
// Weight-stationary main kernel, R9: SOFTWARE-PIPELINED epilogue.
// R6-R8 sat at 51.5us because each wave ran [MFMA block]->[epilogue block]
// serially; with only 2-3 resident waves/SIMD the matrix and VALU pipes
// ping-ponged (VALU idle ~22us). Now iteration g issues:
//    prefetch ub(g+1)  ->  MFMA(g) into acc[g&1]  ->  epilogue(g-1)
// so the ~500-cyc VALU/trans epilogue stream issues WHILE g's MFMAs execute
// on the matrix pipe: one wave keeps both pipes fed regardless of occupancy.
// Costs: double-buffered acc (+16 VGPR) and ub (+16); launch_bounds(256,2).
// Epilogue algebra (proven): scale folded into W1 -> exp2 direct; sum_h W2
// folded into b2eff; paired rcp: one v_rcp per two tanh.
// ---------------------------------------------------------------------------
__global__ __launch_bounds__(256, 2) void branch_mlp(const shortx8* __restrict__ uf,
                                                     const shortx8* __restrict__ wf,
                                                     const float* __restrict__ W2,
                                                     const float* __restrict__ b2eff,
                                                     float* __restrict__ out) {
    int tid = threadIdx.x;
    int lane = tid & 63;
    int w = tid >> 6;
    int bx = blockIdx.x;
    int lat = bx >> 5;
    int G0 = (bx & 31) * 32 + w * 8;
    int q = lane >> 4;

    // latent-resident weights: 16 fragment chunks (64 VGPRs)
    shortx8 afr[4][4];
    const shortx8* wb = wf + (size_t)lat * 16 * 64 + lane;
#pragma unroll
    for (int nt = 0; nt < 4; nt++)
#pragma unroll
        for (int kt = 0; kt < 4; kt++)
            afr[nt][kt] = wb[(nt * 4 + kt) * 64];

    // -2*W2 for this lane's 16 h-values (h = nt*16 + q*4 + r)
    float4 w2v[4];
#pragma unroll
    for (int nt = 0; nt < 4; nt++) {
        float4 t = *(const float4*)(W2 + lat * HIDDEN + nt * 16 + q * 4);
        w2v[nt] = make_float4(-2.0f * t.x, -2.0f * t.y, -2.0f * t.z, -2.0f * t.w);
    }
    float b2v = b2eff[lat];

    const shortx8* ua = uf + (size_t)G0 * 4 * 64 + lane;

    shortx8 ub[2][4];          // ub[g&1] holds group g's fragments
    floatx4 acc[2][4];         // acc[g&1] holds group g's MFMA output
    float sg[8];

    // prologue: load g0, g1; MFMA(0)
#pragma unroll
    for (int kt = 0; kt < 4; kt++) ub[0][kt] = ua[kt * 64];
#pragma unroll
    for (int kt = 0; kt < 4; kt++) ub[1][kt] = ua[(4 + kt) * 64];
#pragma unroll
    for (int nt = 0; nt < 4; nt++) acc[0][nt] = (floatx4){0.f, 0.f, 0.f, 0.f};
#pragma unroll
    for (int kt = 0; kt < 4; kt++)
#pragma unroll
        for (int nt = 0; nt < 4; nt++)
            acc[0][nt] = __builtin_amdgcn_mfma_f32_16x16x32_bf16(afr[nt][kt], ub[0][kt], acc[0][nt], 0, 0, 0);

#pragma unroll
    for (int g = 1; g < 8; g++) {
        int cur = g & 1, prv = cur ^ 1;

        // (1) prefetch ub for g+1 into the buffer g-1 just freed
        if (g < 7) {
#pragma unroll
            for (int kt = 0; kt < 4; kt++)
                ub[prv][kt] = ua[((g + 1) * 4 + kt) * 64];
        }

        // (2) MFMA(g) — matrix pipe chews while (3) issues on VALU
#pragma unroll
        for (int nt = 0; nt < 4; nt++) acc[cur][nt] = (floatx4){0.f, 0.f, 0.f, 0.f};
#pragma unroll
        for (int kt = 0; kt < 4; kt++)
#pragma unroll
            for (int nt = 0; nt < 4; nt++)
                acc[cur][nt] = __builtin_amdgcn_mfma_f32_16x16x32_bf16(afr[nt][kt], ub[cur][kt], acc[cur][nt], 0, 0, 0);

        // (3) epilogue(g-1) from acc[prv]
        {
            float s = 0.0f;
#pragma unroll
            for (int nt = 0; nt < 4; nt++)
#pragma unroll
                for (int r = 0; r < 4; r += 2) {
                    float e0 = EXP2F(acc[prv][nt][r]);       // = exp(2x)
                    float e1 = EXP2F(acc[prv][nt][r + 1]);
                    float d0 = e0 + 1.0f, d1 = e1 + 1.0f;
                    float ip = RCPF(d0 * d1);                // one rcp / two tanh
                    s = fmaf((&w2v[nt].x)[r],     ip * d1, s);
                    s = fmaf((&w2v[nt].x)[r + 1], ip * d0, s);
                }
            sg[g - 1] = s;
        }
    }

    // drain: epilogue(7) from acc[1]
    {
        float s = 0.0f;
#pragma unroll
        for (int nt = 0; nt < 4; nt++)
#pragma unroll
            for (int r = 0; r < 4; r += 2) {
                float e0 = EXP2F(acc[1][nt][r]);
                float e1 = EXP2F(acc[1][nt][r + 1]);
                float d0 = e0 + 1.0f, d1 = e1 + 1.0f;
                float ip = RCPF(d0 * d1);
                s = fmaf((&w2v[nt].x)[r],     ip * d1, s);
                s = fmaf((&w2v[nt].x)[r + 1], ip * d0, s);
            }
        sg[7] = s;
    }

    // deferred cross-quad reductions + stores
#pragma unroll
    for (int g = 0; g < 8; g++) sg[g] += __shfl_xor(sg[g], 16, 64);
#pragma unroll
    for (int g = 0; g < 8; g++) sg[g] += __shfl_xor(sg[g], 32, 64);
    if (lane < 16) {
        float* outp = out + ((size_t)G0 * 16 + lane) * LATENT + lat;
#pragma unroll
        for (int g = 0; g < 8; g++)
            outp[g * 16 * LATENT] = sg[g] + b2v;
    }
}

// --- fp32 fallback (no workspace needed) ---
__global__ __launch_bounds__(256) void fallback_kernel(const float* __restrict__ u, const float* __restrict__ W1,
                                                       const float* __restrict__ b1, const float* __restrict__ W2,
                                                       const float* __restrict__ b2, float* __restrict__ out) {
    int idx = blockIdx.x * 256 + threadIdx.x;
    if (idx >= BATCH * LATENT) return;
    int b = idx >> 7;
    int lat = idx & 127;
    const float* ub = u + b * INDIM;
    float s = 0.0f;
    for (int h = 0; h < HIDDEN; h++) {
        const float* wp = W1 + (lat * HIDDEN + h) * INDIM;
        float dd = b1[lat * HIDDEN + h];
        for (int k = 0; k < INDIM; k++) dd += ub[k] * wp[k];
        s += tanhf(dd) * W2[lat * HIDDEN + h];
    }
    out[idx] = s + b2[lat];
}

extern "C" void kernel_launch(void* const* d_in, const int* in_sizes, int n_in,
                              void* d_out, int out_size, void* d_ws, size_t ws_size,
                              hipStream_t stream) {
    const float* u  = (const float*)d_in[0];
    const float* W1 = (const float*)d_in[1];
    const float* b1 = (const float*)d_in[2];
    const float* W2 = (const float*)d_in[3];
    const float* b2 = (const float*)d_in[4];
    float* out = (float*)d_out;

    const size_t UF_BYTES = (size_t)BATCH * KPAD * 2;           // 4 MiB
    const size_t WF_BYTES = (size_t)LATENT * HIDDEN * KPAD * 2; // 2 MiB
    const size_t B2_BYTES = LATENT * sizeof(float);

    if (ws_size < UF_BYTES + WF_BYTES + B2_BYTES) {
        fallback_kernel<<<(BATCH * LATENT + 255) / 256, 256, 0, stream>>>(u, W1, b1, W2, b2, out);
        return;
    }

    shortx8* uf = (shortx8*)d_ws;
    shortx8* wf = (shortx8*)((char*)d_ws + UF_BYTES);
    float* b2eff = (float*)((char*)d_ws + UF_BYTES + WF_BYTES);

    prep_all<<<N_U_BLK + N_W_BLK + 1, 256, 0, stream>>>(u, W1, b1, W2, b2, uf, wf, b2eff);
    branch_mlp<<<4096, 256, 0, stream>>>(uf, wf, W2, b2eff, out);
}